// Round 5
// baseline (638.437 us; speedup 1.0000x reference)
//
#include <hip/hip_runtime.h>
#include <math.h>

#define N_PART 4096
#define N_T    400
#define N_O    9
#define LOG2PI_F 1.8378770664093453f

typedef float v2f __attribute__((ext_vector_type(2)));

__device__ __forceinline__ v2f v2exp(v2f x){ v2f r; r.x=__expf(x.x); r.y=__expf(x.y); return r; }
__device__ __forceinline__ v2f v2log(v2f x){ v2f r; r.x=__logf(x.x); r.y=__logf(x.y); return r; }
__device__ __forceinline__ v2f v2rcp(v2f x){ v2f r; r.x=__builtin_amdgcn_rcpf(x.x); r.y=__builtin_amdgcn_rcpf(x.y); return r; }
__device__ __forceinline__ v2f v2rsq(v2f x){ v2f r; r.x=__builtin_amdgcn_rsqf(x.x); r.y=__builtin_amdgcn_rsqf(x.y); return r; }

// One full KF/IMM step for 2 particles packed in v2f. Consumes YV[9] (current
// obs), writes the 6-float record, advances wpA/wpB, sets MOUT = marg+EPS'
// (Kc factored out; logs paired outside).
#define KF_STEP(YV, MOUT)                                                      \
{                                                                              \
    const v2f xg  = gi + e0*gc0 + e1*gc1 + e2*gc2;                             \
    const v2f p11 = v2rcp(1.0f + v2exp(-xg));                                  \
    /* prediction */                                                           \
    const v2f ep0 = B00*e0 + B01*e1 + B02*e2;                                  \
    const v2f ep1 = B10*e0 + B11*e1 + B12*e2;                                  \
    const v2f ep2 = B20*e0 + B21*e1 + B22*e2;                                  \
    const v2f ep3 = b2*e3;                                                     \
    const v2f C00 = B00*P00 + B01*P01 + B02*P02;                               \
    const v2f C01 = B00*P01 + B01*P11 + B02*P12;                               \
    const v2f C02 = B00*P02 + B01*P12 + B02*P22;                               \
    const v2f C10 = B10*P00 + B11*P01 + B12*P02;                               \
    const v2f C11 = B10*P01 + B11*P11 + B12*P12;                               \
    const v2f C12 = B10*P02 + B11*P12 + B12*P22;                               \
    const v2f C20 = B20*P00 + B21*P01 + B22*P02;                               \
    const v2f C21 = B20*P01 + B21*P11 + B22*P12;                               \
    const v2f C22 = B20*P02 + B21*P12 + B22*P22;                               \
    const v2f Pp00 = C00*B00 + C01*B01 + C02*B02 + q0;                         \
    const v2f Pp01 = C00*B10 + C01*B11 + C02*B12;                              \
    const v2f Pp02 = C00*B20 + C01*B21 + C02*B22;                              \
    const v2f Pp11 = C10*B10 + C11*B11 + C12*B12 + q1;                         \
    const v2f Pp12 = C10*B20 + C11*B21 + C12*B22;                              \
    const v2f Pp22 = C20*B20 + C21*B21 + C22*B22 + q2;                         \
    const v2f Pp03 = b2*(B00*P03 + B01*P13 + B02*P23);                         \
    const v2f Pp13 = b2*(B10*P03 + B11*P13 + B12*P23);                         \
    const v2f Pp23 = b2*(B20*P03 + B21*P13 + B22*P23);                         \
    const v2f Pp33 = b2*b2*P33 + q3;                                           \
    /* regime 1: Woodbury, diagonal G */                                       \
    v2f v1[9];                                                                 \
    v1[0]=YV[0]-lam1[0]*ep0; v1[1]=YV[1]-lam1[1]*ep0; v1[2]=YV[2]-lam1[2]*ep0; \
    v1[3]=YV[3]-lam1[3]*ep1; v1[4]=YV[4]-lam1[4]*ep1; v1[5]=YV[5]-lam1[5]*ep1; \
    v1[6]=YV[6]-lam1[6]*ep2; v1[7]=YV[7]-lam1[7]*ep2; v1[8]=YV[8]-lam1[8]*ep2; \
    v2f vRv1 = {0,0};                                                          \
    _Pragma("unroll")                                                          \
    for (int o = 0; o < 9; ++o) vRv1 += v1[o]*v1[o]*ri[o];                     \
    const v2f b0  = aA[0]*v1[0] + aA[1]*v1[1] + aA[2]*v1[2];                   \
    const v2f b1  = aA[3]*v1[3] + aA[4]*v1[4] + aA[5]*v1[5];                   \
    const v2f bb2 = aA[6]*v1[6] + aA[7]*v1[7] + aA[8]*v1[8];                   \
    const v2f A00 = 1.0f + gA0*Pp00, A01 = gA0*Pp01, A02 = gA0*Pp02;           \
    const v2f A10 = gA1*Pp01, A11 = 1.0f + gA1*Pp11, A12 = gA1*Pp12;           \
    const v2f A20 = gA2*Pp02, A21 = gA2*Pp12, A22 = 1.0f + gA2*Pp22;           \
    const v2f c00 = A11*A22 - A12*A21;                                         \
    const v2f c01 = A12*A20 - A10*A22;                                         \
    const v2f c02 = A10*A21 - A11*A20;                                         \
    const v2f det = A00*c00 + A01*c01 + A02*c02;                               \
    const v2f idet = v2rcp(det);                                               \
    const v2f Ai00 = c00*idet;                                                 \
    const v2f Ai01 = (A02*A21 - A01*A22)*idet;                                 \
    const v2f Ai02 = (A01*A12 - A02*A11)*idet;                                 \
    const v2f Ai10 = c01*idet;                                                 \
    const v2f Ai11 = (A00*A22 - A02*A20)*idet;                                 \
    const v2f Ai12 = (A02*A10 - A00*A12)*idet;                                 \
    const v2f Ai20 = c02*idet;                                                 \
    const v2f Ai21 = (A01*A20 - A00*A21)*idet;                                 \
    const v2f Ai22 = (A00*A11 - A01*A10)*idet;                                 \
    const v2f u0 = Ai00*b0 + Ai01*b1 + Ai02*bb2;                               \
    const v2f u1 = Ai10*b0 + Ai11*b1 + Ai12*bb2;                               \
    const v2f uu2= Ai20*b0 + Ai21*b1 + Ai22*bb2;                               \
    const v2f sb0 = Pp00*b0 + Pp01*b1 + Pp02*bb2;                              \
    const v2f sb1 = Pp01*b0 + Pp11*b1 + Pp12*bb2;                              \
    const v2f sb2 = Pp02*b0 + Pp12*b1 + Pp22*bb2;                              \
    const v2f qf1 = vRv1 - (u0*sb0 + u1*sb1 + uu2*sb2);                        \
    const v2f e1p = v2rsq(det) * v2exp(-0.5f*qf1);  /* = exp(ll1)/Kc */        \
    const v2f W00 = Ai00*gA0, W01 = Ai01*gA1, W02 = Ai02*gA2;                  \
    const v2f W11 = Ai11*gA1, W12 = Ai12*gA2, W22 = Ai22*gA2;                  \
    const v2f r00=Pp00, r01=Pp01, r02=Pp02;                                    \
    const v2f r10=Pp01, r11=Pp11, r12=Pp12;                                    \
    const v2f r20=Pp02, r21=Pp12, r22=Pp22;                                    \
    const v2f r30=Pp03, r31=Pp13, r32=Pp23;                                    \
    const v2f eta1_0 = ep0 + r00*u0 + r01*u1 + r02*uu2;                        \
    const v2f eta1_1 = ep1 + r10*u0 + r11*u1 + r12*uu2;                        \
    const v2f eta1_2 = ep2 + r20*u0 + r21*u1 + r22*uu2;                        \
    const v2f eta1_3 = ep3 + r30*u0 + r31*u1 + r32*uu2;                        \
    /* regime 2: rank-1 Sherman-Morrison */                                    \
    v2f vRv2 = {0,0}, bv2 = {0,0};                                             \
    _Pragma("unroll")                                                          \
    for (int o = 0; o < 9; ++o) {                                              \
        const v2f v2o = YV[o] - lam2[o]*ep3;                                   \
        vRv2 += v2o*v2o*ri[o];                                                 \
        bv2  += cB[o]*v2o;                                                     \
    }                                                                          \
    const v2f d2den = 1.0f + Pp33*gB;                                          \
    const v2f id2 = v2rcp(d2den);                                              \
    const v2f qf2 = vRv2 - Pp33*id2*bv2*bv2;                                   \
    const v2f e2p = v2rsq(d2den) * v2exp(-0.5f*qf2);                           \
    const v2f kv  = bv2*id2;                                                   \
    const v2f beta = gB*id2;                                                   \
    /* mixing weights (Kc factored out; EPSp = EPS/Kc) */                      \
    const v2f ap  = pr1*p11;                                                   \
    const v2f n1  = e1p*ap;                                                    \
    const v2f n2  = e2p*((pr1 + pr2) - ap);                                    \
    const v2f mt  = n1 + n2 + EPSp;                                            \
    const v2f im  = v2rcp(mt);                                                 \
    const v2f w1  = n1*im;                                                     \
    const v2f w2  = n2*im;                                                     \
    const v2f eta2_0 = ep0 + r30*kv;                                           \
    const v2f eta2_1 = ep1 + r31*kv;                                           \
    const v2f eta2_2 = ep2 + r32*kv;                                           \
    const v2f eta2_3 = ep3 + Pp33*kv;                                          \
    const v2f et0 = w1*eta1_0 + w2*eta2_0;                                     \
    const v2f et1 = w1*eta1_1 + w2*eta2_1;                                     \
    const v2f et2 = w1*eta1_2 + w2*eta2_2;                                     \
    const v2f et3 = w1*eta1_3 + w2*eta2_3;                                     \
    const v2f d1_0=eta1_0-et0, d1_1=eta1_1-et1, d1_2=eta1_2-et2, d1_3=eta1_3-et3; \
    const v2f d2_0=eta2_0-et0, d2_1=eta2_1-et1, d2_2=eta2_2-et2, d2_3=eta2_3-et3; \
    const v2f wd1_0=w1*d1_0, wd1_1=w1*d1_1, wd1_2=w1*d1_2, wd1_3=w1*d1_3;      \
    const v2f wd2_0=w2*d2_0, wd2_1=w2*d2_1, wd2_2=w2*d2_2, wd2_3=w2*d2_3;      \
    /* P = s*Pp - Pc*(w1 W)*Pc^T - (w2 beta) p3 p3^T + wd1 d1^T + wd2 d2^T */  \
    const v2f sw = w1 + w2;                                                    \
    const v2f Wp00=w1*W00, Wp01=w1*W01, Wp02=w1*W02;                           \
    const v2f Wp11=w1*W11, Wp12=w1*W12, Wp22=w1*W22;                           \
    const v2f X00=r00*Wp00+r01*Wp01+r02*Wp02, X01=r00*Wp01+r01*Wp11+r02*Wp12, X02=r00*Wp02+r01*Wp12+r02*Wp22; \
    const v2f X10=r10*Wp00+r11*Wp01+r12*Wp02, X11=r10*Wp01+r11*Wp11+r12*Wp12, X12=r10*Wp02+r11*Wp12+r12*Wp22; \
    const v2f X20=r20*Wp00+r21*Wp01+r22*Wp02, X21=r20*Wp01+r21*Wp11+r22*Wp12, X22=r20*Wp02+r21*Wp12+r22*Wp22; \
    const v2f X30=r30*Wp00+r31*Wp01+r32*Wp02, X31=r30*Wp01+r31*Wp11+r32*Wp12, X32=r30*Wp02+r31*Wp12+r32*Wp22; \
    const v2f bb = w2*beta;                                                    \
    const v2f tb0=bb*r30, tb1=bb*r31, tb2=bb*r32, tb3=bb*Pp33;                 \
    P00 = sw*Pp00 - (X00*r00+X01*r01+X02*r02) - tb0*r30 + wd1_0*d1_0 + wd2_0*d2_0; \
    P01 = sw*Pp01 - (X00*r10+X01*r11+X02*r12) - tb0*r31 + wd1_0*d1_1 + wd2_0*d2_1; \
    P02 = sw*Pp02 - (X00*r20+X01*r21+X02*r22) - tb0*r32 + wd1_0*d1_2 + wd2_0*d2_2; \
    P03 = sw*Pp03 - (X00*r30+X01*r31+X02*r32) - tb0*Pp33+ wd1_0*d1_3 + wd2_0*d2_3; \
    P11 = sw*Pp11 - (X10*r10+X11*r11+X12*r12) - tb1*r31 + wd1_1*d1_1 + wd2_1*d2_1; \
    P12 = sw*Pp12 - (X10*r20+X11*r21+X12*r22) - tb1*r32 + wd1_1*d1_2 + wd2_1*d2_2; \
    P13 = sw*Pp13 - (X10*r30+X11*r31+X12*r32) - tb1*Pp33+ wd1_1*d1_3 + wd2_1*d2_3; \
    P22 = sw*Pp22 - (X20*r20+X21*r21+X22*r22) - tb2*r32 + wd1_2*d1_2 + wd2_2*d2_2; \
    P23 = sw*Pp23 - (X20*r30+X21*r31+X22*r32) - tb2*Pp33+ wd1_2*d1_3 + wd2_2*d2_3; \
    P33 = sw*Pp33 - (X30*r30+X31*r31+X32*r32) - tb3*Pp33+ wd1_3*d1_3 + wd2_3*d2_3; \
    e0 = et0; e1 = et1; e2 = et2; e3 = et3;                                    \
    pr1 = w1; pr2 = w2;                                                        \
    wpA[0]=w1.x; wpA[1]=w2.x; wpA[2]=et0.x; wpA[3]=et1.x; wpA[4]=et2.x; wpA[5]=et3.x; \
    wpB[0]=w1.y; wpB[1]=w2.y; wpB[2]=et0.y; wpB[3]=et1.y; wpB[4]=et2.y; wpB[5]=et3.y; \
    wpA += N_O; wpB += N_O;                                                    \
    MOUT = mt;                                                                 \
}

// 32-thread blocks (half-masked wave64 probe: if HW skips the empty half,
// issue rate doubles; neutral otherwise). 64 blocks x 32 lanes x 2 particles.
__global__ __launch_bounds__(32)
void imm_kf_kernel(const float* __restrict__ y,
                   const float* __restrict__ B1s1,
                   const float* __restrict__ B1s2,
                   const float* __restrict__ l1f,
                   const float* __restrict__ l2f,
                   const float* __restrict__ log_q,
                   const float* __restrict__ log_r,
                   const float* __restrict__ gip,
                   const float* __restrict__ gcp,
                   float* __restrict__ rec,        // ypred region, [N,NT,9] slots
                   float* __restrict__ ll_ws)
{
    const int n = blockIdx.x * 32 + threadIdx.x;   // pair index, 0..2047
    const int pA = 2*n, pB = 2*n + 1;

    // ---- uniform constants ----
    const float B00=B1s1[0],B01=B1s1[1],B02=B1s1[2];
    const float B10=B1s1[3],B11=B1s1[4],B12=B1s1[5];
    const float B20=B1s1[6],B21=B1s1[7],B22=B1s1[8];
    const float b2 = B1s2[0];

    float lam1[9], lam2[9];
    lam1[0]=1.0f; lam1[1]=l1f[0]; lam1[2]=l1f[1];
    lam1[3]=1.0f; lam1[4]=l1f[2]; lam1[5]=l1f[3];
    lam1[6]=1.0f; lam1[7]=l1f[4]; lam1[8]=l1f[5];
    lam2[0]=1.0f;
#pragma unroll
    for (int o = 1; o < 9; ++o) lam2[o] = l2f[o-1];

    const float q0=expf(log_q[0]), q1=expf(log_q[1]), q2=expf(log_q[2]), q3=expf(log_q[3]);

    float ri[9], aA[9], cB[9];
    float logdetR = 0.0f;
    float gA0=0.f, gA1=0.f, gA2=0.f, gB=0.f;
#pragma unroll
    for (int o = 0; o < 9; ++o) {
        const float rr  = expf(log_r[o]);
        const float rj  = rr + 1e-6f;          // R + JITTER folded
        const float riv = 1.0f / rj;
        ri[o] = riv;
        logdetR += logf(rj);
        aA[o] = lam1[o] * riv;
        cB[o] = lam2[o] * riv;
        const float ga = lam1[o]*aA[o];
        if (o < 3) gA0 += ga; else if (o < 6) gA1 += ga; else gA2 += ga;
        gB += lam2[o]*cB[o];
    }
    const float gi  = gip[0];
    const float gc0 = gcp[0], gc1 = gcp[1], gc2 = gcp[2];
    const float llconst = 9.0f * LOG2PI_F + logdetR;
    const float logKc = -0.5f * llconst;          // e_regime = Kc * e'
    const float EPSp  = 1e-9f * __expf(0.5f * llconst);   // EPS / Kc

    // ---- state ----
    v2f P00={1000.f,1000.f}, P01={0,0}, P02={0,0}, P03={0,0};
    v2f P11={1000.f,1000.f}, P12={0,0}, P13={0,0};
    v2f P22={1000.f,1000.f}, P23={0,0};
    v2f P33={1000.f,1000.f};
    v2f e0={0,0}, e1={0,0}, e2={0,0}, e3={0,0};
    v2f pr1={0.99f,0.99f}, pr2={0.01f,0.01f};
    v2f llacc={0,0};

    const float* ybA = y + (size_t)pA * (N_T*N_O);
    const float* ybB = y + (size_t)pB * (N_T*N_O);
    float* wpA = rec + (size_t)pA * (N_T*N_O);
    float* wpB = rec + (size_t)pB * (N_T*N_O);

    v2f ya[9], ybf[9];
#pragma unroll
    for (int o = 0; o < 9; ++o) { ya[o].x = ybA[o]; ya[o].y = ybB[o]; }

    for (int t = 0; t < N_T; t += 2) {
        // prefetch row t+1 into ybf
        const float* rA1 = ybA + (t+1)*N_O;
        const float* rB1 = ybB + (t+1)*N_O;
#pragma unroll
        for (int o = 0; o < 9; ++o) { ybf[o].x = rA1[o]; ybf[o].y = rB1[o]; }

        v2f mA; KF_STEP(ya, mA);

        // prefetch row min(t+2,399) into ya
        const int t2 = (t + 2 <= N_T-1) ? (t + 2) : (N_T-1);
        const float* rA2 = ybA + t2*N_O;
        const float* rB2 = ybB + t2*N_O;
#pragma unroll
        for (int o = 0; o < 9; ++o) { ya[o].x = rA2[o]; ya[o].y = rB2[o]; }

        v2f mB; KF_STEP(ybf, mB);

        llacc += v2log(mA * mB);   // paired logs; m >= EPSp ~5e-6 -> no underflow
    }

    // per-lane: 2 particles x 400 steps of the factored-out log(Kc)
    float lls = llacc.x + llacc.y + 800.0f * logKc;
#pragma unroll
    for (int off = 16; off > 0; off >>= 1)
        lls += __shfl_down(lls, off, 32);
    if (threadIdx.x == 0) atomicAdd(ll_ws, lls);
}

// Expand [w1,w2,e0..e3] records in-place into ypred(9) and probs(2), coalesced.
// 256 slots per block; block 0 also finalizes -ll (stream-ordered after imm_kf).
__global__ __launch_bounds__(256)
void expand_kernel(const float* __restrict__ l1f, const float* __restrict__ l2f,
                   float* __restrict__ ypred, float* __restrict__ probs,
                   const float* __restrict__ ll_ws, float* __restrict__ out0)
{
    __shared__ float buf[2304];
    __shared__ float pbuf[512];
    const int tid = threadIdx.x;
    float* gp = ypred + (size_t)blockIdx.x * 2304;
#pragma unroll
    for (int k = 0; k < 9; ++k) buf[tid + 256*k] = gp[tid + 256*k];

    float lam1[9], lam2[9];
    lam1[0]=1.0f; lam1[1]=l1f[0]; lam1[2]=l1f[1];
    lam1[3]=1.0f; lam1[4]=l1f[2]; lam1[5]=l1f[3];
    lam1[6]=1.0f; lam1[7]=l1f[4]; lam1[8]=l1f[5];
    lam2[0]=1.0f;
#pragma unroll
    for (int o = 1; o < 9; ++o) lam2[o] = l2f[o-1];

    __syncthreads();
    float* r = buf + tid*9;                 // stride 9: odd -> conflict-free
    const float w1=r[0], w2=r[1], f0=r[2], f1=r[3], f2=r[4], f3=r[5];
    const float we0=w1*f0, we1=w1*f1, we2=w1*f2, weB=w2*f3;
    r[0]=lam1[0]*we0+lam2[0]*weB;
    r[1]=lam1[1]*we0+lam2[1]*weB;
    r[2]=lam1[2]*we0+lam2[2]*weB;
    r[3]=lam1[3]*we1+lam2[3]*weB;
    r[4]=lam1[4]*we1+lam2[4]*weB;
    r[5]=lam1[5]*we1+lam2[5]*weB;
    r[6]=lam1[6]*we2+lam2[6]*weB;
    r[7]=lam1[7]*we2+lam2[7]*weB;
    r[8]=lam1[8]*we2+lam2[8]*weB;
    pbuf[tid*2]   = w1;
    pbuf[tid*2+1] = w2;
    __syncthreads();
#pragma unroll
    for (int k = 0; k < 9; ++k) gp[tid + 256*k] = buf[tid + 256*k];
    float* pp = probs + (size_t)blockIdx.x * 512;
    pp[tid]       = pbuf[tid];
    pp[tid + 256] = pbuf[tid + 256];

    if (blockIdx.x == 0 && tid == 0) out0[0] = -ll_ws[0];
}

extern "C" void kernel_launch(void* const* d_in, const int* in_sizes, int n_in,
                              void* d_out, int out_size, void* d_ws, size_t ws_size,
                              hipStream_t stream)
{
    const float* y    = (const float*)d_in[0];
    const float* B1s1 = (const float*)d_in[1];
    const float* B1s2 = (const float*)d_in[2];
    const float* l1f  = (const float*)d_in[3];
    const float* l2f  = (const float*)d_in[4];
    const float* lq   = (const float*)d_in[5];
    const float* lr   = (const float*)d_in[6];
    const float* gi   = (const float*)d_in[7];
    const float* gc   = (const float*)d_in[8];

    float* out   = (float*)d_out;
    float* probs = out + 1;                                    // [N,NT,2]
    float* ypred = out + 1 + (size_t)N_PART * N_T * 2;         // [N,NT,9]
    float* ws    = (float*)d_ws;

    hipMemsetAsync(ws, 0, sizeof(float), stream);
    imm_kf_kernel<<<(N_PART/2)/32, 32, 0, stream>>>(y, B1s1, B1s2, l1f, l2f,
                                                    lq, lr, gi, gc, ypred, ws);
    expand_kernel<<<(N_PART*N_T)/256, 256, 0, stream>>>(l1f, l2f, ypred, probs,
                                                        ws, out);
}